// Round 5
// baseline (270.600 us; speedup 1.0000x reference)
//
#include <hip/hip_runtime.h>
#include <hip/hip_bf16.h>

#define NH 16
#define HD 64
#define EMB 1024
#define BB 4
#define TT 2048
#define MTOT (BB*TT)        // 8192 rows
#define N1 (3*NH*HD)        // 3072
#define KD EMB              // 1024

// q scale: (1/sqrt(HD)) * log2(e) — softmax computed in exp2 domain
#define QSCALE 0.18033688011112042f
// fixed softmax "max" in exp2 domain (exact after 1/l normalization)
#define FMAX 14.0f

typedef __bf16 bf16x8 __attribute__((ext_vector_type(8)));
typedef __bf16 bf16x4 __attribute__((ext_vector_type(4)));
typedef float  f32x4  __attribute__((ext_vector_type(4)));
typedef __hip_bfloat16 hbf;

__device__ __forceinline__ void async_copy16(const hbf* g, hbf* l) {
    __builtin_amdgcn_global_load_lds(
        (const __attribute__((address_space(1))) void*)g,
        (__attribute__((address_space(3))) void*)l, 16, 0, 0);
}

__device__ __forceinline__ bf16x4 pack4(float x0, float x1, float x2, float x3) {
    union { bf16x4 v; hbf a[4]; } u;
    u.a[0] = __float2bfloat16(x0);
    u.a[1] = __float2bfloat16(x1);
    u.a[2] = __float2bfloat16(x2);
    u.a[3] = __float2bfloat16(x3);
    return u.v;
}

// ---------------- conversion kernels ----------------

__global__ __launch_bounds__(256) void f32_to_bf16_v4(const float* __restrict__ in,
                                                      hbf* __restrict__ out, int n4) {
    int i = blockIdx.x * blockDim.x + threadIdx.x;
    if (i < n4) {
        float4 v = ((const float4*)in)[i];
        *(bf16x4*)(out + 4 * (size_t)i) = pack4(v.x, v.y, v.z, v.w);
    }
}

// LDS-tiled transposing convert: out[c*R + r] = bf16(in[r*C + c]); R,C % 64 == 0
__global__ __launch_bounds__(256) void f32_to_bf16_T(const float* __restrict__ in,
                                                     hbf* __restrict__ out, int R, int C) {
    __shared__ float T[64][65];
    int bc = blockIdx.x % (C / 64), br = blockIdx.x / (C / 64);
    int r0 = br * 64, c0 = bc * 64;
    int tr = threadIdx.x >> 6, tc = threadIdx.x & 63;
    #pragma unroll
    for (int i = 0; i < 16; ++i)
        T[4 * i + tr][tc] = in[(size_t)(r0 + 4 * i + tr) * C + c0 + tc];
    __syncthreads();
    #pragma unroll
    for (int i = 0; i < 16; ++i)
        out[(size_t)(c0 + 4 * i + tr) * R + r0 + tc] = __float2bfloat16(T[tc][4 * i + tr]);
}

// ---------------- 8-phase 256x256 GEMM (m201 template port) ----------------
// BM=BN=256, BK=64, 512 thr = 8 waves (2M x 4N); per-wave C = 128x64.
// LDS 128 KB: A,B each 2 buf x 2 half(128x64) x 2B. Half-tile staged as 2
// global_load_lds x16B per thread. XOR swizzle: LDS[row][slot] = G[row][slot^(row&7)].
// Per phase: ds-reads + 1 half-tile stage -> barrier -> lgkmcnt(0)+sched_barrier
// -> setprio(1) 16 MFMA setprio(0) -> barrier. vmcnt(4) only at phase 4 & 8.
// Stage schedule per iter i (tiles 2i->buf0 ph0-3, 2i+1->buf1 ph4-7):
//   ph0: Ah0(2i+1)->b1  ph1: Ah1(2i+1)->b1  ph2: Bh0(2i+2)->b0  ph3: Bh1(2i+2)->b0
//   ph4: Ah0(2i+2)->b0  ph5: Ah1(2i+2)->b0  ph6: Bh0(2i+3)->b1  ph7: Bh1(2i+3)->b1
// MODE 0: qkv scatter epilogue. MODE 1: f32 + bias.

#define GBAR  asm volatile("s_barrier" ::: "memory")
#define GLGKM { asm volatile("s_waitcnt lgkmcnt(0)" ::: "memory"); __builtin_amdgcn_sched_barrier(0); }

template<int NBN, int MODE>
__global__ __launch_bounds__(512, 2) void gemm8p(
    const hbf* __restrict__ A, const hbf* __restrict__ Bt,
    hbf* __restrict__ qh, hbf* __restrict__ kh, hbf* __restrict__ vt,
    const float* __restrict__ bias, float* __restrict__ out)
{
    constexpr int NKT = KD / 64;                 // 16 K-tiles
    constexpr int NIT = NKT / 2;                 // 8 iterations (2 tiles each)
    constexpr int GRID = (MTOT / 256) * NBN;
    __shared__ __align__(16) hbf As[2 * 2 * 8192];   // 64 KB
    __shared__ __align__(16) hbf Bs[2 * 2 * 8192];   // 64 KB

    int tid = threadIdx.x;
    int wv = tid >> 6, lane = tid & 63;
    int g = lane >> 4, c = lane & 15;
    int wm = wv >> 2, wn = wv & 3;               // 2M x 4N waves
    int xr = c & 7;
    // bijective XCD swizzle (GRID % 8 == 0)
    int wg = (blockIdx.x & 7) * (GRID / 8) + (blockIdx.x >> 3);
    int bn = wg % NBN, bm = wg / NBN;
    int m0 = bm * 256, n0 = bn * 256;

    // staging: per half-tile (128x64), thread does chunks tid (rows 0-63) and
    // 512+tid (rows 64-127); slot = tid&7, global k-chunk = slot ^ (row&7)
    int r0 = tid >> 3;
    int gc = (tid & 7) ^ (r0 & 7);
    const hbf* pA = A  + (size_t)(m0 + r0) * KD + gc * 8;
    const hbf* pB = Bt + (size_t)(n0 + r0) * KD + gc * 8;
    int ldsd = (tid & ~63) * 8;

#define STG_A(t, buf, hf) { \
    async_copy16(pA + (size_t)((hf)*128     ) * KD + (t)*64, As + (buf)*16384 + (hf)*8192 + ldsd); \
    async_copy16(pA + (size_t)((hf)*128 + 64) * KD + (t)*64, As + (buf)*16384 + (hf)*8192 + 4096 + ldsd); }
#define STG_B(t, buf, hf) { \
    async_copy16(pB + (size_t)((hf)*128     ) * KD + (t)*64, Bs + (buf)*16384 + (hf)*8192 + ldsd); \
    async_copy16(pB + (size_t)((hf)*128 + 64) * KD + (t)*64, Bs + (buf)*16384 + (hf)*8192 + 4096 + ldsd); }

    bf16x8 af[4][2];          // A frags: 4 mi x 2 kk (one mh at a time)
    bf16x8 bfr[2][2][2];      // B frags: 2 nq x 2 ni x 2 kk (whole tile cached)
    f32x4 acc[2][2][4][2];    // [mh][nq][mi][ni]
    #pragma unroll
    for (int a0 = 0; a0 < 2; ++a0)
      #pragma unroll
      for (int a1 = 0; a1 < 2; ++a1)
        #pragma unroll
        for (int a2 = 0; a2 < 4; ++a2)
          #pragma unroll
          for (int a3 = 0; a3 < 2; ++a3) acc[a0][a1][a2][a3] = (f32x4){0.f,0.f,0.f,0.f};

#define LDA(buf, mh) { _Pragma("unroll") for (int mi = 0; mi < 4; ++mi) { \
    const hbf* ap = As + (buf)*16384 + wm*8192 + ((mh)*64 + mi*16 + c)*64; \
    af[mi][0] = *(const bf16x8*)(ap + ((g ^ xr) << 3)); \
    af[mi][1] = *(const bf16x8*)(ap + (((4 + g) ^ xr) << 3)); } }
#define LDB(buf, nq) { _Pragma("unroll") for (int ni = 0; ni < 2; ++ni) { \
    const hbf* bp = Bs + (buf)*16384 + (wn >> 1)*8192 + ((wn & 1)*64 + (nq)*32 + ni*16 + c)*64; \
    bfr[nq][ni][0] = *(const bf16x8*)(bp + ((g ^ xr) << 3)); \
    bfr[nq][ni][1] = *(const bf16x8*)(bp + (((4 + g) ^ xr) << 3)); } }
#define MM(mh, nq) { __builtin_amdgcn_s_setprio(1); \
    _Pragma("unroll") for (int mi = 0; mi < 4; ++mi) \
      _Pragma("unroll") for (int ni = 0; ni < 2; ++ni) { \
        acc[mh][nq][mi][ni] = __builtin_amdgcn_mfma_f32_16x16x32_bf16(af[mi][0], bfr[nq][ni][0], acc[mh][nq][mi][ni], 0, 0, 0); \
        acc[mh][nq][mi][ni] = __builtin_amdgcn_mfma_f32_16x16x32_bf16(af[mi][1], bfr[nq][ni][1], acc[mh][nq][mi][ni], 0, 0, 0); } \
    __builtin_amdgcn_s_setprio(0); }

    // prologue: tile0 (A+B) -> buf0; B(1) -> buf1. vmcnt(4) keeps B(1) in flight.
    STG_A(0, 0, 0); STG_A(0, 0, 1); STG_B(0, 0, 0); STG_B(0, 0, 1);
    STG_B(1, 1, 0); STG_B(1, 1, 1);
    asm volatile("s_waitcnt vmcnt(4)" ::: "memory");
    GBAR;
    __builtin_amdgcn_sched_barrier(0);

    for (int i = 0; i < NIT - 1; ++i) {
        // ph0: tile 2i (buf0), quadrant (0,0)
        LDA(0, 0); LDB(0, 0); STG_A(2*i+1, 1, 0);
        GBAR; GLGKM; MM(0, 0); GBAR;
        // ph1: (0,1)
        LDB(0, 1); STG_A(2*i+1, 1, 1);
        GBAR; GLGKM; MM(0, 1); GBAR;
        // ph2: (1,0)
        LDA(0, 1); STG_B(2*i+2, 0, 0);
        GBAR; GLGKM; MM(1, 0); GBAR;
        // ph3: (1,1); counted wait: keep ph2,ph3 stages (4 loads) in flight
        STG_B(2*i+2, 0, 1);
        GBAR; MM(1, 1);
        asm volatile("s_waitcnt vmcnt(4)" ::: "memory");
        GBAR;
        // ph4: tile 2i+1 (buf1), (0,0)
        LDA(1, 0); LDB(1, 0); STG_A(2*i+2, 0, 0);
        GBAR; GLGKM; MM(0, 0); GBAR;
        // ph5: (0,1)
        LDB(1, 1); STG_A(2*i+2, 0, 1);
        GBAR; GLGKM; MM(0, 1); GBAR;
        // ph6: (1,0)
        LDA(1, 1); STG_B(2*i+3, 1, 0);
        GBAR; GLGKM; MM(1, 0); GBAR;
        // ph7: (1,1); keep ph6,ph7 stages in flight
        STG_B(2*i+3, 1, 1);
        GBAR; MM(1, 1);
        asm volatile("s_waitcnt vmcnt(4)" ::: "memory");
        GBAR;
        __builtin_amdgcn_sched_barrier(0);
    }
    // peeled final iteration (tiles NKT-2 buf0, NKT-1 buf1); stages only A(NKT-1)
    {
        LDA(0, 0); LDB(0, 0); STG_A(NKT-1, 1, 0);
        GBAR; GLGKM; MM(0, 0); GBAR;
        LDB(0, 1); STG_A(NKT-1, 1, 1);
        GBAR; GLGKM; MM(0, 1); GBAR;
        LDA(0, 1);
        GBAR; GLGKM; MM(1, 0); GBAR;
        MM(1, 1);
        asm volatile("s_waitcnt vmcnt(0)" ::: "memory");
        GBAR;
        LDA(1, 0); LDB(1, 0);
        GBAR; GLGKM; MM(0, 0); GBAR;
        LDB(1, 1);
        GBAR; GLGKM; MM(0, 1); GBAR;
        LDA(1, 1);
        GBAR; GLGKM; MM(1, 0); GBAR;
        MM(1, 1);
    }
#undef STG_A
#undef STG_B
#undef LDA
#undef LDB
#undef MM

    if constexpr (MODE == 0) {
        int colbase = n0 + wn * 64;                  // one full head per wave
        int which = colbase >> 10;                   // 0:q 1:k 2:v
        int h = (colbase & 1023) >> 6;
        int b = m0 / TT;
        int trow0 = (m0 % TT) + wm * 128;
        if (which < 2) {
            float scale = (which == 0) ? QSCALE : 1.0f;
            hbf* dst = ((which == 0) ? qh : kh) + ((size_t)b * NH + h) * TT * HD;
            #pragma unroll
            for (int mh = 0; mh < 2; ++mh)
              #pragma unroll
              for (int mi = 0; mi < 4; ++mi)
                #pragma unroll
                for (int nq = 0; nq < 2; ++nq)
                  #pragma unroll
                  for (int ni = 0; ni < 2; ++ni) {
                      int d = nq * 32 + ni * 16 + c;
                      #pragma unroll
                      for (int r = 0; r < 4; ++r) {
                          int t = trow0 + mh * 64 + mi * 16 + g * 4 + r;
                          dst[(size_t)t * HD + d] = __float2bfloat16(acc[mh][nq][mi][ni][r] * scale);
                      }
                  }
        } else {
            hbf* dst = vt + ((size_t)b * NH + h) * TT * HD;   // [HD][TT] per head
            #pragma unroll
            for (int mh = 0; mh < 2; ++mh)
              #pragma unroll
              for (int mi = 0; mi < 4; ++mi)
                #pragma unroll
                for (int nq = 0; nq < 2; ++nq)
                  #pragma unroll
                  for (int ni = 0; ni < 2; ++ni) {
                      int d = nq * 32 + ni * 16 + c;
                      #pragma unroll
                      for (int r = 0; r < 4; ++r) {
                          int t = trow0 + mh * 64 + mi * 16 + g * 4 + r;
                          dst[(size_t)d * TT + t] = __float2bfloat16(acc[mh][nq][mi][ni][r]);
                      }
                  }
        }
    } else {
        #pragma unroll
        for (int mh = 0; mh < 2; ++mh)
          #pragma unroll
          for (int mi = 0; mi < 4; ++mi)
            #pragma unroll
            for (int nq = 0; nq < 2; ++nq)
              #pragma unroll
              for (int ni = 0; ni < 2; ++ni) {
                  int col = n0 + wn * 64 + nq * 32 + ni * 16 + c;
                  float bv = bias[col];
                  #pragma unroll
                  for (int r = 0; r < 4; ++r) {
                      int row = m0 + wm * 128 + mh * 64 + mi * 16 + g * 4 + r;
                      out[(size_t)row * EMB + col] = acc[mh][nq][mi][ni][r] + bv;
                  }
              }
    }
}

// ---------------- flash attention v5x: v5 (proven 74us) + XCD-major bh map ----------------
// Block = 512 thr = 8 waves, 128-q supertile (wave wv owns q rows qb+16wv..+15).
// Stage K[128x64] + V^T[64x128] per step (global_load_lds, XOR-swizzled source).
// S^T = K·Q^T with C seeded to -FMAX (fixed-max softmax, exact after 1/l).
// l via ones-MFMA. Causal balance: block runs supertile pair (pi, 15-pi).
// bidx: [0:3)=bh-low (XCD), [3:6)=pi, [6:9)=bh-high -> same-bh blocks share an XCD
// (K/V stay L2-resident: r4 measured FETCH 147->24.6 MB with this map).

__global__ __launch_bounds__(512, 4) void attn(
    const hbf* __restrict__ qh, const hbf* __restrict__ kh, const hbf* __restrict__ vt,
    hbf* __restrict__ y)
{
    __shared__ __align__(16) hbf Ks[128 * 64];     // 16 KB [key][dim-swz]
    __shared__ __align__(16) hbf Vs[64 * 128];     // 16 KB [dim][key-swz]
    __shared__ __align__(16) hbf Ps[8][16 * 64];   // 16 KB per-wave P^T

    int tid = threadIdx.x;
    int wv = tid >> 6, lane = tid & 63;
    int g = lane >> 4, c = lane & 15;
    int c7 = c & 7;

    int bidx = blockIdx.x;
    int bh = (bidx & 7) | (((bidx >> 6) & 7) << 3);
    int pi = (bidx >> 3) & 7;
    int b = bh >> 4, h = bh & 15;

    const hbf* Q = qh + (size_t)bh * TT * HD;
    const hbf* K = kh + (size_t)bh * TT * HD;
    const hbf* V = vt + (size_t)bh * TT * HD;   // [HD][TT]
    hbf* Pq = &Ps[wv][0];

    union { bf16x8 v; hbf a[8]; } uo;
    #pragma unroll
    for (int i = 0; i < 8; ++i) uo.a[i] = __float2bfloat16(1.0f);
    const bf16x8 ones8 = uo.v;

    #pragma unroll
    for (int pass = 0; pass < 2; ++pass) {
        int sst = pass ? (15 - pi) : pi;
        int qb = sst * 128;
        int q0 = qb + wv * 16;
        int kend = q0 + 16;
        int kmax = qb + 128;

        bf16x8 aq0 = *(const bf16x8*)(Q + (size_t)(q0 + c) * HD + g * 8);
        bf16x8 aq1 = *(const bf16x8*)(Q + (size_t)(q0 + c) * HD + 32 + g * 8);

        f32x4 lacc = (f32x4){0.f, 0.f, 0.f, 0.f};
        f32x4 o[4];
        #pragma unroll
        for (int d = 0; d < 4; ++d) o[d] = (f32x4){0.f, 0.f, 0.f, 0.f};

        for (int k0 = 0; k0 < kmax; k0 += 128) {
            __syncthreads();   // prior stage's LDS reads complete
            #pragma unroll
            for (int it = 0; it < 2; ++it) {
                int e = it * 4096 + tid * 8;
                int key = e >> 6, sblk = (e >> 3) & 7;
                int dblk = sblk ^ (key & 7);
                async_copy16(K + (size_t)(k0 + key) * HD + dblk * 8,
                             Ks + it * 4096 + (tid & ~63) * 8);
            }
            #pragma unroll
            for (int it = 0; it < 2; ++it) {
                int e = it * 4096 + tid * 8;
                int dim = e >> 7, kb = (e >> 3) & 15;
                int skb = kb ^ (dim & 7);
                async_copy16(V + (size_t)dim * TT + k0 + skb * 8,
                             Vs + it * 4096 + (tid & ~63) * 8);
            }
            __syncthreads();   // staged

            #pragma unroll
            for (int ch = 0; ch < 2; ++ch) {
                int c64 = k0 + ch * 64;
                if (c64 < kend) {                         // wave-uniform
                    f32x4 s[4];
                    #pragma unroll
                    for (int t = 0; t < 4; ++t) {
                        int kt = c64 + 16 * t;
                        if (kt < kend) {                  // wave-uniform
                            int rb = (ch * 64 + 16 * t + c) * 64;
                            bf16x8 kf0 = *(const bf16x8*)(Ks + rb + ((g ^ c7) << 3));
                            bf16x8 kf1 = *(const bf16x8*)(Ks + rb + (((4 + g) ^ c7) << 3));
                            f32x4 a = (f32x4){-FMAX, -FMAX, -FMAX, -FMAX};
                            a = __builtin_amdgcn_mfma_f32_16x16x32_bf16(kf0, aq0, a, 0, 0, 0);
                            a = __builtin_amdgcn_mfma_f32_16x16x32_bf16(kf1, aq1, a, 0, 0, 0);
                            if (kt == q0) {               // diagonal: key<=q ⇔ g*4+r<=c
                                #pragma unroll
                                for (int r = 0; r < 4; ++r)
                                    a[r] = (g * 4 + r <= c) ? a[r] : -1e30f;
                            }
                            s[t] = a;
                        } else
                            s[t] = (f32x4){-1e30f, -1e30f, -1e30f, -1e30f};
                    }
                    #pragma unroll
                    for (int t = 0; t < 4; ++t) {
                        f32x4 e;
                        #pragma unroll
                        for (int r = 0; r < 4; ++r) e[r] = __builtin_amdgcn_exp2f(s[t][r]);
                        *(bf16x4*)(Pq + c * 64 + (((2 * t + (g >> 1)) ^ c7) << 3) + ((g & 1) << 2)) =
                            pack4(e[0], e[1], e[2], e[3]);
                    }
                    #pragma unroll
                    for (int sc = 0; sc < 2; ++sc) {
                        if (c64 + 32 * sc < kend) {       // wave-uniform
                            bf16x8 pf = *(const bf16x8*)(Pq + c * 64 + (((4 * sc + g) ^ c7) << 3));
                            lacc = __builtin_amdgcn_mfma_f32_16x16x32_bf16(ones8, pf, lacc, 0, 0, 0);
                            #pragma unroll
                            for (int d = 0; d < 4; ++d) {
                                int dim = d * 16 + c;
                                bf16x8 vf = *(const bf16x8*)(Vs + dim * 128 +
                                              (((ch * 8 + 4 * sc + g) ^ c7) << 3));
                                o[d] = __builtin_amdgcn_mfma_f32_16x16x32_bf16(vf, pf, o[d], 0, 0, 0);
                            }
                        }
                    }
                }
            }
        }

        float inv = 1.0f / lacc[0];
        #pragma unroll
        for (int d = 0; d < 4; ++d) {
            *(bf16x4*)(y + (size_t)(b * TT + q0 + c) * EMB + h * HD + d * 16 + g * 4) =
                pack4(o[d][0] * inv, o[d][1] * inv, o[d][2] * inv, o[d][3] * inv);
        }
    }
}

// ---------------- launch ----------------

extern "C" void kernel_launch(void* const* d_in, const int* in_sizes, int n_in,
                              void* d_out, int out_size, void* d_ws, size_t ws_size,
                              hipStream_t stream)
{
    const float* x      = (const float*)d_in[0];
    const float* W_attn = (const float*)d_in[1];
    const float* W_proj = (const float*)d_in[2];
    const float* b_proj = (const float*)d_in[3];
    float* out = (float*)d_out;

    char* ws = (char*)d_ws;
    hbf* xb    = (hbf*)ws; ws += (size_t)MTOT * KD * 2;
    hbf* wab_t = (hbf*)ws; ws += (size_t)N1 * KD * 2;
    hbf* wpb_t = (hbf*)ws; ws += (size_t)EMB * EMB * 2;
    hbf* qh    = (hbf*)ws; ws += (size_t)MTOT * EMB * 2;
    hbf* kh    = (hbf*)ws; ws += (size_t)MTOT * EMB * 2;
    hbf* vt    = (hbf*)ws; ws += (size_t)MTOT * EMB * 2;
    hbf* yb    = (hbf*)ws; ws += (size_t)MTOT * EMB * 2;

    f32_to_bf16_v4<<<(MTOT * KD / 4 + 255) / 256, 256, 0, stream>>>(x, xb, MTOT * KD / 4);
    f32_to_bf16_T<<<(KD / 64) * (N1 / 64), 256, 0, stream>>>(W_attn, wab_t, KD, N1);
    f32_to_bf16_T<<<(KD / 64) * (EMB / 64), 256, 0, stream>>>(W_proj, wpb_t, KD, EMB);

    gemm8p<N1 / 256, 0><<<(MTOT / 256) * (N1 / 256), 512, 0, stream>>>(
        xb, wab_t, qh, kh, vt, nullptr, nullptr);
    attn<<<BB * NH * 8, 512, 0, stream>>>(qh, kh, vt, yb);
    gemm8p<EMB / 256, 1><<<(MTOT / 256) * (EMB / 256), 512, 0, stream>>>(
        yb, wpb_t, nullptr, nullptr, nullptr, b_proj, out);
}

// Round 8
// 250.902 us; speedup vs baseline: 1.0785x; 1.0785x over previous
//
#include <hip/hip_runtime.h>
#include <hip/hip_bf16.h>

#define NH 16
#define HD 64
#define EMB 1024
#define BB 4
#define TT 2048
#define MTOT (BB*TT)        // 8192 rows
#define N1 (3*NH*HD)        // 3072
#define KD EMB              // 1024

// q scale: (1/sqrt(HD)) * log2(e) — softmax computed in exp2 domain
#define QSCALE 0.18033688011112042f
// fixed softmax "max" in exp2 domain (exact after 1/l normalization)
#define FMAX 14.0f

typedef __bf16 bf16x8 __attribute__((ext_vector_type(8)));
typedef __bf16 bf16x4 __attribute__((ext_vector_type(4)));
typedef float  f32x4  __attribute__((ext_vector_type(4)));
typedef __hip_bfloat16 hbf;

__device__ __forceinline__ void async_copy16(const hbf* g, hbf* l) {
    __builtin_amdgcn_global_load_lds(
        (const __attribute__((address_space(1))) void*)g,
        (__attribute__((address_space(3))) void*)l, 16, 0, 0);
}

__device__ __forceinline__ bf16x4 pack4(float x0, float x1, float x2, float x3) {
    union { bf16x4 v; hbf a[4]; } u;
    u.a[0] = __float2bfloat16(x0);
    u.a[1] = __float2bfloat16(x1);
    u.a[2] = __float2bfloat16(x2);
    u.a[3] = __float2bfloat16(x3);
    return u.v;
}

// ---------------- conversion kernels (r0-r5 proven) ----------------

__global__ __launch_bounds__(256) void f32_to_bf16_v4(const float* __restrict__ in,
                                                      hbf* __restrict__ out, int n4) {
    int i = blockIdx.x * blockDim.x + threadIdx.x;
    if (i < n4) {
        float4 v = ((const float4*)in)[i];
        *(bf16x4*)(out + 4 * (size_t)i) = pack4(v.x, v.y, v.z, v.w);
    }
}

// LDS-tiled transposing convert: out[c*R + r] = bf16(in[r*C + c]); R,C % 64 == 0
__global__ __launch_bounds__(256) void f32_to_bf16_T(const float* __restrict__ in,
                                                     hbf* __restrict__ out, int R, int C) {
    __shared__ float T[64][65];
    int bc = blockIdx.x % (C / 64), br = blockIdx.x / (C / 64);
    int r0 = br * 64, c0 = bc * 64;
    int tr = threadIdx.x >> 6, tc = threadIdx.x & 63;
    #pragma unroll
    for (int i = 0; i < 16; ++i)
        T[4 * i + tr][tc] = in[(size_t)(r0 + 4 * i + tr) * C + c0 + tc];
    __syncthreads();
    #pragma unroll
    for (int i = 0; i < 16; ++i)
        out[(size_t)(c0 + 4 * i + tr) * R + r0 + tc] = __float2bfloat16(T[tc][4 * i + tr]);
}

// ---------------- GEMM v2: 64x64 wave tiles, BK=32, lead-2 counted-vmcnt pipeline ----
// 256 thr = 4 waves (2x2), block 128x128, LDS 32KB dbuf -> 4 blocks/CU.
// 8 ds_read_b128 per 16 MFMA. Stage t+2 into just-freed buffer behind
// lgkmcnt(0)+barrier; one counted vmcnt(4) per tile (never 0 in-loop).
// XOR swizzle: slot = chunk ^ (row&3) at stage-source and frag-read.
// MODE 0: qkv scatter epilogue. MODE 1: f32 + bias.  (r4-verified)

template<int NBN, int MODE>
__global__ __launch_bounds__(256, 4) void gemm_v2(
    const hbf* __restrict__ A, const hbf* __restrict__ Bt,
    hbf* __restrict__ qh, hbf* __restrict__ kh, hbf* __restrict__ vt,
    const float* __restrict__ bias, float* __restrict__ out)
{
    constexpr int NKT = KD / 32;                 // 32 K-tiles
    __shared__ __align__(16) hbf As[2 * 128 * 32];   // 16 KB
    __shared__ __align__(16) hbf Bs[2 * 128 * 32];   // 16 KB

    int tid = threadIdx.x;
    int wv = tid >> 6, lane = tid & 63;
    int g = lane >> 4, c = lane & 15;
    int wm = wv >> 1, wn = wv & 1;               // 2x2 waves; wave out = 64x64
    int wg = (blockIdx.x & 7) * (8 * NBN) + (blockIdx.x >> 3);
    int bn = wg % NBN, bm = wg / NBN;
    int m0 = bm * 128, n0 = bn * 128;

    int sr = tid >> 2;
    int sgc = (tid & 3) ^ (sr & 3);
    const hbf* Asrc0 = A  + (size_t)(m0 + sr) * KD + sgc * 8;
    const hbf* Asrc1 = A  + (size_t)(m0 + 64 + sr) * KD + sgc * 8;
    const hbf* Bsrc0 = Bt + (size_t)(n0 + sr) * KD + sgc * 8;
    const hbf* Bsrc1 = Bt + (size_t)(n0 + 64 + sr) * KD + sgc * 8;
    int ld0 = (tid & ~63) * 8, ld1 = 2048 + (tid & ~63) * 8;

#define STG(tt, buf) { \
    async_copy16(Asrc0 + (tt) * 32, As + (buf) * 4096 + ld0); \
    async_copy16(Asrc1 + (tt) * 32, As + (buf) * 4096 + ld1); \
    async_copy16(Bsrc0 + (tt) * 32, Bs + (buf) * 4096 + ld0); \
    async_copy16(Bsrc1 + (tt) * 32, Bs + (buf) * 4096 + ld1); }

    int x3 = c & 3;
    int ao = (wm * 64 + c) * 32 + ((g ^ x3) << 3);
    int bo = (wn * 64 + c) * 32 + ((g ^ x3) << 3);

    f32x4 acc[4][4];
    #pragma unroll
    for (int i = 0; i < 4; ++i)
        #pragma unroll
        for (int j = 0; j < 4; ++j) acc[i][j] = (f32x4){0.f, 0.f, 0.f, 0.f};

    STG(0, 0);
    STG(1, 1);
    asm volatile("s_waitcnt vmcnt(4)" ::: "memory");
    asm volatile("s_barrier" ::: "memory");
    __builtin_amdgcn_sched_barrier(0);

    for (int t = 0; t < NKT; ++t) {
        int cur = t & 1;
        const hbf* Ab = As + cur * 4096;
        const hbf* Bb = Bs + cur * 4096;
        bf16x8 af[4], bfr[4];
        #pragma unroll
        for (int i = 0; i < 4; ++i) af[i] = *(const bf16x8*)(Ab + ao + i * 512);
        #pragma unroll
        for (int j = 0; j < 4; ++j) bfr[j] = *(const bf16x8*)(Bb + bo + j * 512);
        asm volatile("s_waitcnt lgkmcnt(0)" ::: "memory");
        __builtin_amdgcn_sched_barrier(0);
        asm volatile("s_barrier" ::: "memory");
        __builtin_amdgcn_sched_barrier(0);
        if (t + 2 < NKT) STG(t + 2, cur);
        __builtin_amdgcn_s_setprio(1);
        #pragma unroll
        for (int i = 0; i < 4; ++i)
            #pragma unroll
            for (int j = 0; j < 4; ++j)
                acc[i][j] = __builtin_amdgcn_mfma_f32_16x16x32_bf16(af[i], bfr[j], acc[i][j], 0, 0, 0);
        __builtin_amdgcn_s_setprio(0);
        if (t + 2 < NKT) { asm volatile("s_waitcnt vmcnt(4)" ::: "memory"); }
        else             { asm volatile("s_waitcnt vmcnt(0)" ::: "memory"); }
        asm volatile("s_barrier" ::: "memory");
        __builtin_amdgcn_sched_barrier(0);
    }
#undef STG

    if constexpr (MODE == 0) {
        int colbase = n0 + wn * 64;
        int which = colbase >> 10;
        int h = (colbase & 1023) >> 6;
        int b = m0 / TT;
        int trow = (m0 % TT) + wm * 64;
        if (which < 2) {
            float scale = (which == 0) ? QSCALE : 1.0f;
            hbf* dst = ((which == 0) ? qh : kh) + ((size_t)b * NH + h) * TT * HD;
            #pragma unroll
            for (int i = 0; i < 4; ++i)
                #pragma unroll
                for (int j = 0; j < 4; ++j) {
                    int d = j * 16 + c;
                    #pragma unroll
                    for (int r = 0; r < 4; ++r) {
                        int trw = trow + i * 16 + g * 4 + r;
                        dst[(size_t)trw * HD + d] = __float2bfloat16(acc[i][j][r] * scale);
                    }
                }
        } else {
            hbf* dst = vt + ((size_t)b * NH + h) * TT * HD;   // [HD][TT] per head
            #pragma unroll
            for (int i = 0; i < 4; ++i)
                #pragma unroll
                for (int j = 0; j < 4; ++j) {
                    int d = j * 16 + c;
                    #pragma unroll
                    for (int r = 0; r < 4; ++r) {
                        int trw = trow + i * 16 + g * 4 + r;
                        dst[(size_t)d * TT + trw] = __float2bfloat16(acc[i][j][r]);
                    }
                }
        }
    } else {
        #pragma unroll
        for (int i = 0; i < 4; ++i)
            #pragma unroll
            for (int j = 0; j < 4; ++j) {
                int col = n0 + wn * 64 + j * 16 + c;
                float bv = bias[col];
                #pragma unroll
                for (int r = 0; r < 4; ++r) {
                    int row = m0 + wm * 64 + i * 16 + g * 4 + r;
                    out[(size_t)row * EMB + col] = acc[i][j][r] + bv;
                }
            }
    }
}

// ---------------- flash attention v7: v5x + double-buffered 128-key stages ----------------
// Block = 512 thr = 8 waves, supertile pair (pi, 15-pi), 128-key K/V stages.
// K/V LDS double-buffered (80 KB total -> 2 blocks/CU; grid already caps at 2).
// Per stage: compute buf[s&1] -> barrier -> refill buf[s&1] with stage s+2 ->
// counted vmcnt(4) (never 0 in-loop) -> barrier. Removes the per-stage HBM drain.
// Fixed-max softmax in exp2 domain; l via ones-MFMA. XCD-major bh map (r4: FETCH 147->24.6MB).

__global__ __launch_bounds__(512, 4) void attn(
    const hbf* __restrict__ qh, const hbf* __restrict__ kh, const hbf* __restrict__ vt,
    hbf* __restrict__ y)
{
    __shared__ __align__(16) hbf Ks[2 * 128 * 64];   // 32 KB [key][dim-swz] dbuf
    __shared__ __align__(16) hbf Vs[2 * 64 * 128];   // 32 KB [dim][key-swz] dbuf
    __shared__ __align__(16) hbf Ps[8][16 * 64];     // 16 KB per-wave P^T

    int tid = threadIdx.x;
    int wv = tid >> 6, lane = tid & 63;
    int g = lane >> 4, c = lane & 15;
    int c7 = c & 7;

    int bidx = blockIdx.x;
    int bh = (bidx & 7) | (((bidx >> 6) & 7) << 3);
    int pi = (bidx >> 3) & 7;
    int b = bh >> 4, h = bh & 15;

    const hbf* Q = qh + (size_t)bh * TT * HD;
    const hbf* K = kh + (size_t)bh * TT * HD;
    const hbf* V = vt + (size_t)bh * TT * HD;   // [HD][TT]
    hbf* Pq = &Ps[wv][0];

#define ASTG(ss, buf) { \
    int k0s = (ss) * 128; \
    _Pragma("unroll") for (int it = 0; it < 2; ++it) { \
        int e = it * 4096 + tid * 8; \
        int key = e >> 6, sblk = (e >> 3) & 7; \
        int dblk = sblk ^ (key & 7); \
        async_copy16(K + (size_t)(k0s + key) * HD + dblk * 8, \
                     Ks + (buf) * 8192 + it * 4096 + (tid & ~63) * 8); } \
    _Pragma("unroll") for (int it = 0; it < 2; ++it) { \
        int e = it * 4096 + tid * 8; \
        int dim = e >> 7, kb = (e >> 3) & 15; \
        int skb = kb ^ (dim & 7); \
        async_copy16(V + (size_t)dim * TT + k0s + skb * 8, \
                     Vs + (buf) * 8192 + it * 4096 + (tid & ~63) * 8); } }

    union { bf16x8 v; hbf a[8]; } uo;
    #pragma unroll
    for (int i = 0; i < 8; ++i) uo.a[i] = __float2bfloat16(1.0f);
    const bf16x8 ones8 = uo.v;

    #pragma unroll
    for (int pass = 0; pass < 2; ++pass) {
        int sst = pass ? (15 - pi) : pi;
        int qb = sst * 128;
        int q0 = qb + wv * 16;
        int kend = q0 + 16;
        int S = sst + 1;                         // 128-key stages this pass

        bf16x8 aq0 = *(const bf16x8*)(Q + (size_t)(q0 + c) * HD + g * 8);
        bf16x8 aq1 = *(const bf16x8*)(Q + (size_t)(q0 + c) * HD + 32 + g * 8);

        f32x4 lacc = (f32x4){0.f, 0.f, 0.f, 0.f};
        f32x4 o[4];
        #pragma unroll
        for (int d = 0; d < 4; ++d) o[d] = (f32x4){0.f, 0.f, 0.f, 0.f};

        // prologue: stage 0 (and 1) — only stage 0 must land before compute
        ASTG(0, 0);
        if (S > 1) {
            ASTG(1, 1);
            asm volatile("s_waitcnt vmcnt(4)" ::: "memory");
        } else {
            asm volatile("s_waitcnt vmcnt(0)" ::: "memory");
        }
        asm volatile("s_barrier" ::: "memory");
        __builtin_amdgcn_sched_barrier(0);

        for (int s = 0; s < S; ++s) {
            int k0 = s * 128;
            const hbf* Kb = Ks + (s & 1) * 8192;
            const hbf* Vb = Vs + (s & 1) * 8192;

            #pragma unroll
            for (int ch = 0; ch < 2; ++ch) {
                int c64 = k0 + ch * 64;
                if (c64 < kend) {                         // wave-uniform
                    f32x4 sv[4];
                    #pragma unroll
                    for (int t = 0; t < 4; ++t) {
                        int kt = c64 + 16 * t;
                        if (kt < kend) {                  // wave-uniform
                            int rb = (ch * 64 + 16 * t + c) * 64;
                            bf16x8 kf0 = *(const bf16x8*)(Kb + rb + ((g ^ c7) << 3));
                            bf16x8 kf1 = *(const bf16x8*)(Kb + rb + (((4 + g) ^ c7) << 3));
                            f32x4 a = (f32x4){-FMAX, -FMAX, -FMAX, -FMAX};
                            a = __builtin_amdgcn_mfma_f32_16x16x32_bf16(kf0, aq0, a, 0, 0, 0);
                            a = __builtin_amdgcn_mfma_f32_16x16x32_bf16(kf1, aq1, a, 0, 0, 0);
                            if (kt == q0) {               // diagonal: key<=q ⇔ g*4+r<=c
                                #pragma unroll
                                for (int r = 0; r < 4; ++r)
                                    a[r] = (g * 4 + r <= c) ? a[r] : -1e30f;
                            }
                            sv[t] = a;
                        } else
                            sv[t] = (f32x4){-1e30f, -1e30f, -1e30f, -1e30f};
                    }
                    #pragma unroll
                    for (int t = 0; t < 4; ++t) {
                        f32x4 e;
                        #pragma unroll
                        for (int r = 0; r < 4; ++r) e[r] = __builtin_amdgcn_exp2f(sv[t][r]);
                        *(bf16x4*)(Pq + c * 64 + (((2 * t + (g >> 1)) ^ c7) << 3) + ((g & 1) << 2)) =
                            pack4(e[0], e[1], e[2], e[3]);
                    }
                    #pragma unroll
                    for (int sc = 0; sc < 2; ++sc) {
                        if (c64 + 32 * sc < kend) {       // wave-uniform
                            bf16x8 pf = *(const bf16x8*)(Pq + c * 64 + (((4 * sc + g) ^ c7) << 3));
                            lacc = __builtin_amdgcn_mfma_f32_16x16x32_bf16(ones8, pf, lacc, 0, 0, 0);
                            #pragma unroll
                            for (int d = 0; d < 4; ++d) {
                                int dim = d * 16 + c;
                                bf16x8 vf = *(const bf16x8*)(Vb + dim * 128 +
                                              (((ch * 8 + 4 * sc + g) ^ c7) << 3));
                                o[d] = __builtin_amdgcn_mfma_f32_16x16x32_bf16(vf, pf, o[d], 0, 0, 0);
                            }
                        }
                    }
                }
            }

            asm volatile("s_barrier" ::: "memory");       // all waves done with buf[s&1]
            __builtin_amdgcn_sched_barrier(0);
            if (s + 2 < S) {
                ASTG(s + 2, s & 1);                       // refill freed buffer
                asm volatile("s_waitcnt vmcnt(4)" ::: "memory");   // stage s+1 landed
            } else if (s + 1 < S) {
                asm volatile("s_waitcnt vmcnt(0)" ::: "memory");   // last refill landed
            }
            asm volatile("s_barrier" ::: "memory");       // buf[(s+1)&1] ready for all
            __builtin_amdgcn_sched_barrier(0);
        }

        float inv = 1.0f / lacc[0];
        #pragma unroll
        for (int d = 0; d < 4; ++d) {
            *(bf16x4*)(y + (size_t)(b * TT + q0 + c) * EMB + h * HD + d * 16 + g * 4) =
                pack4(o[d][0] * inv, o[d][1] * inv, o[d][2] * inv, o[d][3] * inv);
        }
    }
#undef ASTG
}

// ---------------- launch ----------------

extern "C" void kernel_launch(void* const* d_in, const int* in_sizes, int n_in,
                              void* d_out, int out_size, void* d_ws, size_t ws_size,
                              hipStream_t stream)
{
    const float* x      = (const float*)d_in[0];
    const float* W_attn = (const float*)d_in[1];
    const float* W_proj = (const float*)d_in[2];
    const float* b_proj = (const float*)d_in[3];
    float* out = (float*)d_out;

    char* ws = (char*)d_ws;
    hbf* xb    = (hbf*)ws; ws += (size_t)MTOT * KD * 2;
    hbf* wab_t = (hbf*)ws; ws += (size_t)N1 * KD * 2;
    hbf* wpb_t = (hbf*)ws; ws += (size_t)EMB * EMB * 2;
    hbf* qh    = (hbf*)ws; ws += (size_t)MTOT * EMB * 2;
    hbf* kh    = (hbf*)ws; ws += (size_t)MTOT * EMB * 2;
    hbf* vt    = (hbf*)ws; ws += (size_t)MTOT * EMB * 2;
    hbf* yb    = (hbf*)ws; ws += (size_t)MTOT * EMB * 2;

    f32_to_bf16_v4<<<(MTOT * KD / 4 + 255) / 256, 256, 0, stream>>>(x, xb, MTOT * KD / 4);
    f32_to_bf16_T<<<(KD / 64) * (N1 / 64), 256, 0, stream>>>(W_attn, wab_t, KD, N1);
    f32_to_bf16_T<<<(KD / 64) * (EMB / 64), 256, 0, stream>>>(W_proj, wpb_t, KD, EMB);

    gemm_v2<N1 / 128, 0><<<(MTOT / 128) * (N1 / 128), 256, 0, stream>>>(
        xb, wab_t, qh, kh, vt, nullptr, nullptr);
    attn<<<BB * NH * 8, 512, 0, stream>>>(qh, kh, vt, yb);
    gemm_v2<EMB / 128, 1><<<(MTOT / 128) * (EMB / 128), 256, 0, stream>>>(
        yb, wpb_t, nullptr, nullptr, nullptr, b_proj, out);
}